// Round 4
// baseline (232.740 us; speedup 1.0000x reference)
//
#include <hip/hip_runtime.h>
#include <hip/hip_bf16.h>
#include <cstdint>
#include <cstddef>

#define EMB_K   1024
#define EMB_C   256
#define HWB     4096        // 64*64 per batch
#define NPIX    65536       // 16*4096

typedef __bf16 bf16x8 __attribute__((ext_vector_type(8)));
typedef float  f32x4  __attribute__((ext_vector_type(4)));

__device__ __forceinline__ unsigned short bf16bits(float v) {
  __hip_bfloat16 h = __float2bfloat16(v);
  return __builtin_bit_cast(unsigned short, h);
}

// ---- emb -> bf16 + fp32 norms; zero loss ----
__global__ void k_emb(const float* __restrict__ emb, unsigned short* __restrict__ emb_bf,
                      float* __restrict__ enorm, float* __restrict__ loss) {
  int k = blockIdx.x;      // 0..1023
  int c = threadIdx.x;     // 0..255
  if (k == 0 && c == 0) *loss = 0.f;
  float v = emb[(size_t)k * EMB_C + c];
  emb_bf[(size_t)k * EMB_C + c] = bf16bits(v);
  float s = v * v;
  for (int m = 32; m; m >>= 1) s += __shfl_down(s, m, 64);
  __shared__ float red[4];
  int lane = c & 63, w = c >> 6;
  if (lane == 0) red[w] = s;
  __syncthreads();
  if (c == 0) enorm[k] = red[0] + red[1] + red[2] + red[3];
}

// ================= mega kernel =================
// 256 blocks x 512 threads. Block owns 256 n-rows (one b, 256 consecutive hw)
// and ALL 1024 k. 8 waves = 4 n-groups (g) x 2 k-halves (h). Each wave:
// 64 n-rows x 512 k. A (64n x 256c bf16) lives in VGPRs; B staged in LDS
// (both halves, 128KB) in 4 segments of 128k each.
// LDS map: [0,131072) Bs | +131072 keys_l[256] | +132096 xn_l[256] | +133120 red[16]
#define LDS_BYTES 133184

__global__ __launch_bounds__(512, 2) void
k_mega(const float* __restrict__ x, const float* __restrict__ emb,
       const unsigned short* __restrict__ embbf, const float* __restrict__ enorm,
       float* __restrict__ out, float* __restrict__ loss) {
  extern __shared__ char smem[];
  unsigned char* Bs = (unsigned char*)smem;
  unsigned* keys_l  = (unsigned*)(smem + 131072);
  float*    xn_l    = (float*)(smem + 132096);
  float*    red     = (float*)(smem + 133120);

  int n0  = blockIdx.x * 256;
  int b   = n0 >> 12;        // batch
  int hw0 = n0 & 4095;       // hw base (multiple of 256)
  int t    = threadIdx.x;
  int wave = t >> 6, lane = t & 63;
  int g = wave >> 1;         // n-group 0..3
  int h = wave & 1;          // k-half 0..1
  int quad = lane >> 4, lr = lane & 15;

  if (t < 256) keys_l[t] = 0u;

  // ---------- A prologue: x -> bf16 fragments in registers + xnorm ----------
  // xls: [32 c][257 f32] staging tile (reuses Bs region), 8 chunks of 32 c.
  bf16x8 af[4][8];           // [row-tile i][s-step]  (128 VGPRs)
  float xn[4] = {0.f, 0.f, 0.f, 0.f};
  const float* xb = x + (size_t)b * (EMB_C * HWB) + hw0;
  float* xls = (float*)smem;
#pragma unroll
  for (int ch = 0; ch < 8; ++ch) {
    __syncthreads();
    {
      int c_loc = t >> 4, f16 = t & 15;
#pragma unroll
      for (int m = 0; m < 4; ++m) {
        int f4 = f16 + m * 16;
        f32x4 v = *(const f32x4*)(xb + (size_t)(ch * 32 + c_loc) * HWB + f4 * 4);
        float* dp = xls + c_loc * 257 + f4 * 4;
        dp[0] = v[0]; dp[1] = v[1]; dp[2] = v[2]; dp[3] = v[3];
      }
    }
    __syncthreads();
#pragma unroll
    for (int i = 0; i < 4; ++i) {
      int row = g * 64 + i * 16 + lr;
      unsigned u[4];
#pragma unroll
      for (int m = 0; m < 4; ++m) {
        float v0 = xls[(quad * 8 + 2 * m)     * 257 + row];
        float v1 = xls[(quad * 8 + 2 * m + 1) * 257 + row];
        xn[i] += v0 * v0 + v1 * v1;
        u[m] = (unsigned)bf16bits(v0) | ((unsigned)bf16bits(v1) << 16);
      }
      union { unsigned uu[4]; bf16x8 v; } cv;
      cv.uu[0] = u[0]; cv.uu[1] = u[1]; cv.uu[2] = u[2]; cv.uu[3] = u[3];
      af[i][ch] = cv.v;
    }
  }
  // xnorm: sum quads (both h-waves computed same rows; h==0 writes)
#pragma unroll
  for (int i = 0; i < 4; ++i) {
    xn[i] += __shfl_xor(xn[i], 16, 64);
    xn[i] += __shfl_xor(xn[i], 32, 64);
  }
  if (h == 0 && quad == 0) {
#pragma unroll
    for (int i = 0; i < 4; ++i) xn_l[g * 64 + i * 16 + lr] = xn[i];
  }

  // ---------- K-loop: 4 segments x (2 halves x 128 k-rows) ----------
  unsigned best[4][4] = {{0u,0u,0u,0u},{0u,0u,0u,0u},{0u,0u,0u,0u},{0u,0u,0u,0u}};

  for (int iter = 0; iter < 4; ++iter) {
    __syncthreads();   // xls / previous B reads complete
    // stage both halves: 8192 x 16B chunks, XOR-swizzled within 128B groups
#pragma unroll
    for (int j = 0; j < 16; ++j) {
      int d    = j * 512 + t;          // dest chunk id (= linear LDS order)
      int half = d >> 12;
      int r    = (d >> 5) & 127;       // row within half
      int slot = d & 31;
      int c16  = ((slot >> 3) << 3) | ((slot & 7) ^ (r & 7));
      int kabs = half * 512 + iter * 128 + r;
      const unsigned short* src = embbf + (size_t)kabs * EMB_C + c16 * 8;
      __builtin_amdgcn_global_load_lds(
          (const __attribute__((address_space(1))) void*)src,
          (__attribute__((address_space(3))) void*)(Bs + (unsigned)(j * 8192 + wave * 1024)),
          16, 0, 0);
    }
    // bias terms for this wave's 8 k-tiles in the segment
    float cjseg[8];
#pragma unroll
    for (int kt = 0; kt < 8; ++kt)
      cjseg[kt] = 0.375f - 0.5f * enorm[h * 512 + iter * 128 + kt * 16 + lr];
    __syncthreads();

#pragma unroll
    for (int kt = 0; kt < 8; ++kt) {
      f32x4 acc[4] = {};
      int rowB = h * 128 + kt * 16 + lr;
#pragma unroll
      for (int s = 0; s < 8; ++s) {
        int slot = ((s >> 1) << 3) | ((((s & 1) * 4 + quad)) ^ (lr & 7));
        bf16x8 bfv = *(const bf16x8*)(Bs + rowB * 512 + slot * 16);
#pragma unroll
        for (int i = 0; i < 4; ++i)
          acc[i] = __builtin_amdgcn_mfma_f32_16x16x32_bf16(af[i][s], bfv, acc[i], 0, 0, 0);
      }
      // fold into best-keys: f = dot + 0.375 - 0.5*||e||^2 in (0.04, 0.71);
      // positive-float u32 order-correct; low 10 bits carry (1023-k).
      unsigned kp = (unsigned)(1023 - (h * 512 + iter * 128 + kt * 16) - lr);
#pragma unroll
      for (int i = 0; i < 4; ++i)
#pragma unroll
        for (int r = 0; r < 4; ++r) {
          float f = acc[i][r] + cjseg[kt];
          unsigned key = (__float_as_uint(f) & 0xFFFFFC00u) | kp;
          best[i][r] = best[i][r] > key ? best[i][r] : key;
        }
    }
  }

  // ---------- reduce keys across the 16 k-lanes, combine halves in LDS ----------
#pragma unroll
  for (int i = 0; i < 4; ++i)
#pragma unroll
    for (int r = 0; r < 4; ++r) {
      unsigned v = best[i][r];
#pragma unroll
      for (int m = 1; m < 16; m <<= 1) {
        unsigned o = (unsigned)__shfl_xor((int)v, m, 64);
        v = v > o ? v : o;
      }
      if (lr == 0) atomicMax(&keys_l[g * 64 + i * 16 + quad * 4 + r], v);
    }
  __syncthreads();

  // ---------- loss partials (exact xnorm + truncated-dot) ----------
  float lsum = 0.f;
  if (t < 256) {
    unsigned key = keys_l[t];
    float fh = __uint_as_float(key & 0xFFFFFC00u);
    lsum = xn_l[t] + 0.75f - 2.0f * fh;   // d2 = ||x||^2 + ||e||^2 - 2 dot
  }
  for (int m = 32; m; m >>= 1) lsum += __shfl_down(lsum, m, 64);
  if (lane == 0 && wave < 4) red[wave] = lsum;

  // ---------- quant output: wave (w&3) owns 64 n, (w>>2) picks c-half ----------
  int nl  = (wave & 3) * 64 + lane;
  int ch0 = (wave >> 2) * 128;
  int idx = 1023 - (int)(keys_l[nl] & 1023u);
  const float* er = emb + (size_t)idx * EMB_C + ch0;
  float* ob = out + 1 + (size_t)b * (EMB_C * HWB) + (size_t)ch0 * HWB + hw0 + nl;
#pragma unroll
  for (int cc = 0; cc < 32; ++cc) {
    f32x4 q = *(const f32x4*)(er + cc * 4);    // L2-resident emb gather
    ob[(size_t)(cc * 4 + 0) * HWB] = q[0];
    ob[(size_t)(cc * 4 + 1) * HWB] = q[1];
    ob[(size_t)(cc * 4 + 2) * HWB] = q[2];
    ob[(size_t)(cc * 4 + 3) * HWB] = q[3];
  }
  __syncthreads();
  if (t == 0) atomicAdd(loss, red[0] + red[1] + red[2] + red[3]);
}

// ---------------- finalize scalar loss ----------------
__global__ void k_fin(const float* __restrict__ loss, float* __restrict__ out) {
  out[0] = 1.0625f * (*loss) / 16777216.0f;   // (1 + 0.25*0.25) * mse
}

extern "C" void kernel_launch(void* const* d_in, const int* in_sizes, int n_in,
                              void* d_out, int out_size, void* d_ws, size_t ws_size,
                              hipStream_t stream) {
  const float* x   = (const float*)d_in[0];   // [16,256,64,64]
  const float* emb = (const float*)d_in[1];   // [1024,256]
  float* out = (float*)d_out;                 // [1 + 16777216]
  char*  ws  = (char*)d_ws;

  unsigned short* emb_bf = (unsigned short*)ws;                 // 512 KB
  float*          enorm  = (float*)(ws + 524288);               // 4 KB
  float*          loss   = (float*)(ws + 528384);               // 4 B

  // allow >64KB dynamic LDS (idempotent; not a stream op, capture-safe)
  static bool attr_done = false;
  (void)attr_done;
  hipFuncSetAttribute((const void*)k_mega,
                      hipFuncAttributeMaxDynamicSharedMemorySize, LDS_BYTES);

  k_emb <<<dim3(EMB_K), dim3(EMB_C), 0, stream>>>(emb, emb_bf, enorm, loss);
  k_mega<<<dim3(NPIX / 256), dim3(512), LDS_BYTES, stream>>>(x, emb, emb_bf, enorm, out, loss);
  k_fin <<<dim3(1), dim3(1), 0, stream>>>(loss, out);
}

// Round 5
// 218.334 us; speedup vs baseline: 1.0660x; 1.0660x over previous
//
#include <hip/hip_runtime.h>
#include <hip/hip_bf16.h>
#include <cstdint>
#include <cstddef>

#define EMB_K   1024
#define EMB_C   256
#define HWB     4096        // 64*64 per batch
#define NPIX    65536       // 16*4096

typedef __bf16 bf16x8 __attribute__((ext_vector_type(8)));
typedef float  f32x4  __attribute__((ext_vector_type(4)));

__device__ __forceinline__ unsigned short bf16bits(float v) {
  __hip_bfloat16 h = __float2bfloat16(v);
  return __builtin_bit_cast(unsigned short, h);
}

// ---- emb -> bf16 + fp32 norms; zero keys + loss + ctr ----
__global__ void k_emb(const float* __restrict__ emb, unsigned short* __restrict__ emb_bf,
                      float* __restrict__ enorm, unsigned* __restrict__ keys,
                      float* __restrict__ loss, unsigned* __restrict__ ctr) {
  int k = blockIdx.x;      // 0..1023
  int c = threadIdx.x;     // 0..255
  if (c < 64) keys[k * 64 + c] = 0u;
  if (k == 0 && c == 0) { *loss = 0.f; *ctr = 0u; }
  float v = emb[(size_t)k * EMB_C + c];
  emb_bf[(size_t)k * EMB_C + c] = bf16bits(v);
  float s = v * v;
  for (int m = 32; m; m >>= 1) s += __shfl_down(s, m, 64);
  __shared__ float red[4];
  int lane = c & 63, w = c >> 6;
  if (lane == 0) red[w] = s;
  __syncthreads();
  if (c == 0) enorm[k] = red[0] + red[1] + red[2] + red[3];
}

// ---- x [b][c][hw] fp32 -> xT [n][c] bf16 + xnorm[n]; f32x4 loads ----
__global__ void k_xt(const float* __restrict__ x, unsigned short* __restrict__ xT,
                     float* __restrict__ xnorm) {
  __shared__ unsigned short tile[64][66];   // [c_local][hw], stride 66 shorts
  __shared__ float xnred[64];
  int hw0 = blockIdx.x * 64;
  int b   = blockIdx.y;
  int n0  = b * HWB + hw0;
  int t   = threadIdx.x;
  int hwq = t & 15;        // hw quad 0..15 (covers hw = hwq*4 .. +3)
  int cl  = t >> 4;        // 0..15
  if (t < 64) xnred[t] = 0.f;
  float xn0 = 0.f, xn1 = 0.f, xn2 = 0.f, xn3 = 0.f;
  const float* xb = x + (size_t)b * EMB_C * HWB;
  for (int chunk = 0; chunk < 4; ++chunk) {
    int c0 = chunk * 64;
    __syncthreads();
#pragma unroll
    for (int j = 0; j < 4; ++j) {
      int clocal = j * 16 + cl;
      f32x4 v = *(const f32x4*)(xb + (size_t)(c0 + clocal) * HWB + hw0 + hwq * 4);
      xn0 += v[0] * v[0]; xn1 += v[1] * v[1];
      xn2 += v[2] * v[2]; xn3 += v[3] * v[3];
      unsigned p0 = (unsigned)bf16bits(v[0]) | ((unsigned)bf16bits(v[1]) << 16);
      unsigned p1 = (unsigned)bf16bits(v[2]) | ((unsigned)bf16bits(v[3]) << 16);
      unsigned* base = (unsigned*)((unsigned short*)tile + clocal * 66 + hwq * 4);
      base[0] = p0; base[1] = p1;
    }
    __syncthreads();
#pragma unroll
    for (int it = 0; it < 4; ++it) {
      int id = it * 256 + t;
      int cq = id & 15;        // c quad
      int r  = id >> 4;        // hw row 0..63
      unsigned s0 = tile[cq * 4 + 0][r];
      unsigned s1 = tile[cq * 4 + 1][r];
      unsigned s2 = tile[cq * 4 + 2][r];
      unsigned s3 = tile[cq * 4 + 3][r];
      uint2 val = { s0 | (s1 << 16), s2 | (s3 << 16) };
      *(uint2*)(xT + (size_t)(n0 + r) * EMB_C + c0 + cq * 4) = val;
    }
  }
  atomicAdd(&xnred[hwq * 4 + 0], xn0);
  atomicAdd(&xnred[hwq * 4 + 1], xn1);
  atomicAdd(&xnred[hwq * 4 + 2], xn2);
  atomicAdd(&xnred[hwq * 4 + 3], xn3);
  __syncthreads();
  if (t < 64) xnorm[n0 + t] = xnred[t];
}

// ---------------- GEMM + fused argmin (R2-proven structure) ----------------
#define BM 128
#define BN 128
#define BK 64

__global__ __launch_bounds__(256) void
k_gemm(const unsigned short* __restrict__ xT, const unsigned short* __restrict__ embbf,
       const float* __restrict__ enorm, unsigned* __restrict__ keys) {
  __shared__ __attribute__((aligned(16))) unsigned char As[BM * BK * 2];  // 16 KB
  __shared__ __attribute__((aligned(16))) unsigned char Bs[BN * BK * 2];  // 16 KB
  int k0 = blockIdx.x * BN;
  int n0 = blockIdx.y * BM;
  int tid  = threadIdx.x;
  int wave = tid >> 6, lane = tid & 63;
  int wm = wave >> 1, wn = wave & 1;
  int quad = lane >> 4, lr = lane & 15;

  f32x4 acc[4][4] = {};

#pragma unroll
  for (int ct = 0; ct < EMB_C; ct += BK) {
    if (ct) __syncthreads();
#pragma unroll
    for (int j = 0; j < 4; ++j) {
      int gg = j * 256 + tid;          // chunk id 0..1023
      int r  = gg >> 3;                // tile row 0..127
      int jc = (gg & 7) ^ (r & 7);     // swizzled 16B-chunk within row
      unsigned lds_off = (unsigned)(j * 4096 + (tid >> 6) * 1024);  // wave-uniform
      const unsigned short* ga = xT    + (size_t)(n0 + r) * EMB_C + ct + jc * 8;
      const unsigned short* gb = embbf + (size_t)(k0 + r) * EMB_C + ct + jc * 8;
      __builtin_amdgcn_global_load_lds((const __attribute__((address_space(1))) void*)ga,
                                       (__attribute__((address_space(3))) void*)(As + lds_off),
                                       16, 0, 0);
      __builtin_amdgcn_global_load_lds((const __attribute__((address_space(1))) void*)gb,
                                       (__attribute__((address_space(3))) void*)(Bs + lds_off),
                                       16, 0, 0);
    }
    __syncthreads();
#pragma unroll
    for (int s = 0; s < 2; ++s) {
      bf16x8 af[4], bfv[4];
#pragma unroll
      for (int i = 0; i < 4; ++i) {
        int r  = wm * 64 + i * 16 + lr;
        int ch = (s * 4 + quad) ^ (r & 7);
        af[i]  = *(const bf16x8*)(As + r * 128 + ch * 16);
        int rk  = wn * 64 + i * 16 + lr;
        int chb = (s * 4 + quad) ^ (rk & 7);
        bfv[i]  = *(const bf16x8*)(Bs + rk * 128 + chb * 16);
      }
#pragma unroll
      for (int i = 0; i < 4; ++i)
#pragma unroll
        for (int jj = 0; jj < 4; ++jj)
          acc[i][jj] = __builtin_amdgcn_mfma_f32_16x16x32_bf16(af[i], bfv[jj], acc[i][jj], 0, 0, 0);
    }
  }

  // argmax of f = dot + (0.375 - 0.5*enorm[k]); f in (0.04, 0.71) -> positive-float
  // u32 compare order-correct; low 10 mantissa bits carry (1023-k).
  float    cj[4];
  unsigned kp[4];
#pragma unroll
  for (int j = 0; j < 4; ++j) {
    int k = k0 + wn * 64 + j * 16 + lr;
    cj[j] = 0.375f - 0.5f * enorm[k];
    kp[j] = 1023u - (unsigned)k;
  }
#pragma unroll
  for (int i = 0; i < 4; ++i) {
#pragma unroll
    for (int r = 0; r < 4; ++r) {
      unsigned best = 0u;
#pragma unroll
      for (int j = 0; j < 4; ++j) {
        float f = acc[i][j][r] + cj[j];
        unsigned key = (__float_as_uint(f) & 0xFFFFFC00u) | kp[j];
        best = best > key ? best : key;
      }
#pragma unroll
      for (int m = 1; m < 16; m <<= 1) {
        unsigned o = (unsigned)__shfl_xor((int)best, m, 64);
        best = best > o ? best : o;
      }
      if (lr == 0) {
        int n = n0 + wm * 64 + i * 16 + quad * 4 + r;
        atomicMax(&keys[n], best);
      }
    }
  }
}

// -------- epilogue v2: LDS-transposed gather->store + fused loss finalize --------
__global__ __launch_bounds__(512) void
k_epi(const float* __restrict__ emb, const unsigned* __restrict__ keys,
      const float* __restrict__ xnorm, float* __restrict__ out,
      float* __restrict__ loss, unsigned* __restrict__ ctr) {
  __shared__ float tile[64][257];   // [n_local][c] fp32, ~65.8 KB
  __shared__ int   idx_s[128];
  __shared__ float red[8];
  int n0  = blockIdx.x * 128;
  int b   = n0 >> 12;
  int hw0 = n0 & 4095;
  int t    = threadIdx.x;
  int lane = t & 63, w = t >> 6;

  float lsum = 0.f;
  if (t < 128) {
    unsigned key = keys[n0 + t];
    idx_s[t] = 1023 - (int)(key & 1023u);
    float fh = __uint_as_float(key & 0xFFFFFC00u);
    lsum = xnorm[n0 + t] + 0.75f - 2.0f * fh;   // d2 = ||x||^2 + ||e||^2 - 2 dot
  }
  for (int m = 32; m; m >>= 1) lsum += __shfl_down(lsum, m, 64);
  if (lane == 0) red[w] = lsum;
  __syncthreads();

  // fused finalize: loss-add then counter; last block writes out[0]
  if (t == 0) {
    float part = red[0] + red[1];
    atomicAdd(loss, part);
    __threadfence();
    unsigned done = atomicAdd(ctr, 1u);
    if (done == gridDim.x - 1) {
      float total = atomicAdd(loss, 0.f);   // device-scope read of final sum
      out[0] = 1.0625f * total / 16777216.0f;
    }
  }

  float* ob = out + 1 + (size_t)b * (EMB_C * HWB) + hw0;
  for (int pass = 0; pass < 2; ++pass) {
    if (pass) __syncthreads();
    // gather: 64 rows x 256 c fp32; 8 threads per row, 8 f32x4 each
    int nl   = t >> 3;
    int cseg = (t & 7) * 32;
    const float* er = emb + (size_t)idx_s[pass * 64 + nl] * EMB_C + cseg;
    float* dst = &tile[nl][cseg];
#pragma unroll
    for (int m = 0; m < 8; ++m) {
      f32x4 q = *(const f32x4*)(er + m * 4);
      dst[m * 4 + 0] = q[0]; dst[m * 4 + 1] = q[1];
      dst[m * 4 + 2] = q[2]; dst[m * 4 + 3] = q[3];
    }
    __syncthreads();
    // store c-major: per instr, 64 lanes write 256B contiguous; LDS col read 2-way/free
#pragma unroll
    for (int s = 0; s < 32; ++s) {
      int id  = s * 512 + t;
      int c   = id >> 6;
      int hwL = id & 63;
      ob[(size_t)c * HWB + pass * 64 + hwL] = tile[hwL][c];
    }
  }
}

extern "C" void kernel_launch(void* const* d_in, const int* in_sizes, int n_in,
                              void* d_out, int out_size, void* d_ws, size_t ws_size,
                              hipStream_t stream) {
  const float* x   = (const float*)d_in[0];   // [16,256,64,64]
  const float* emb = (const float*)d_in[1];   // [1024,256]
  float* out = (float*)d_out;                 // [1 + 16777216]
  char*  ws  = (char*)d_ws;

  unsigned short* emb_bf = (unsigned short*)ws;                 // 512 KB
  float*          enorm  = (float*)(ws + 524288);               // 4 KB
  unsigned*       keys   = (unsigned*)(ws + 528384);            // 256 KB
  float*          xnorm  = (float*)(ws + 790528);               // 256 KB
  float*          loss   = (float*)(ws + 1052672);              // 4 B
  unsigned*       ctr    = (unsigned*)(ws + 1052676);           // 4 B

  size_t xt_need = 1052736 + (size_t)NPIX * EMB_C * 2;          // ~34.6 MB
  unsigned short* xT;
  if (ws_size >= xt_need) {
    xT = (unsigned short*)(ws + 1052736);
  } else {
    // scratch inside d_out's quant region; k_gemm consumes xT before k_epi writes out
    xT = (unsigned short*)((char*)d_out + 16);
  }

  k_emb <<<dim3(EMB_K), dim3(EMB_C), 0, stream>>>(emb, emb_bf, enorm, keys, loss, ctr);
  k_xt  <<<dim3(64, 16), dim3(256), 0, stream>>>(x, xT, xnorm);
  k_gemm<<<dim3(EMB_K / BN, NPIX / BM), dim3(256), 0, stream>>>(xT, emb_bf, enorm, keys);
  k_epi <<<dim3(NPIX / 128), dim3(512), 0, stream>>>(emb, keys, xnorm, out, loss, ctr);
}

// Round 6
// 177.085 us; speedup vs baseline: 1.3143x; 1.2329x over previous
//
#include <hip/hip_runtime.h>
#include <hip/hip_bf16.h>
#include <cstdint>
#include <cstddef>

#define EMB_K   1024
#define EMB_C   256
#define HWB     4096        // 64*64 per batch
#define NPIX    65536       // 16*4096

typedef __bf16 bf16x8 __attribute__((ext_vector_type(8)));
typedef float  f32x4  __attribute__((ext_vector_type(4)));

__device__ __forceinline__ unsigned short bf16bits(float v) {
  __hip_bfloat16 h = __float2bfloat16(v);
  return __builtin_bit_cast(unsigned short, h);
}

// ---- emb -> bf16 + fp32 norms; zero loss + ctr ----
__global__ void k_emb(const float* __restrict__ emb, unsigned short* __restrict__ emb_bf,
                      float* __restrict__ enorm, float* __restrict__ loss,
                      unsigned* __restrict__ ctr) {
  int k = blockIdx.x;      // 0..1023
  int c = threadIdx.x;     // 0..255
  if (k == 0 && c == 0) { *loss = 0.f; *ctr = 0u; }
  float v = emb[(size_t)k * EMB_C + c];
  emb_bf[(size_t)k * EMB_C + c] = bf16bits(v);
  float s = v * v;
  for (int m = 32; m; m >>= 1) s += __shfl_down(s, m, 64);
  __shared__ float red[4];
  int lane = c & 63, w = c >> 6;
  if (lane == 0) red[w] = s;
  __syncthreads();
  if (c == 0) enorm[k] = red[0] + red[1] + red[2] + red[3];
}

// ---- B staging: 128k x 256c bf16 = 64KB, XOR-swizzled 16B chunks, glds ----
__device__ __forceinline__ void stage_b(const unsigned short* __restrict__ embbf,
                                        unsigned char* buf, int kt, int t) {
#pragma unroll
  for (int j = 0; j < 8; ++j) {
    int d = j * 512 + t;             // linear dest chunk
    int r = d >> 5;                  // k-row 0..127
    int slot = d & 31;
    int c16 = ((slot >> 3) << 3) | ((slot & 7) ^ (r & 7));
    const unsigned short* src = embbf + (size_t)(kt * 128 + r) * EMB_C + c16 * 8;
    __builtin_amdgcn_global_load_lds(
        (const __attribute__((address_space(1))) void*)src,
        (__attribute__((address_space(3))) void*)(buf + (unsigned)(j * 8192 + (t >> 6) * 1024)),
        16, 0, 0);
  }
}

// ================= fused main kernel =================
// 512 blocks x 512 threads, 1 block/CU (133KB LDS). Block owns 128 n (one b,
// 128 consecutive hw) and ALL 1024 k. Waves: g=w>>1 n-group (32n), h=w&1 k-half
// (64k of each 128k tile). A (32n x 256c) in registers (af[2][8], 64 VGPRs).
// B double-buffered in LDS; argmin + loss + output all complete in-block.
// LDS: [0,64K) A/tile/Bbuf1 | [64K,128K) Bbuf0 | cjl | keys_l | xn_l | red
#define LDS_BYTES 136224

__global__ __launch_bounds__(512, 2) void
k_main(const float* __restrict__ x, const float* __restrict__ emb,
       const unsigned short* __restrict__ embbf, const float* __restrict__ enorm,
       float* __restrict__ out, float* __restrict__ loss, unsigned* __restrict__ ctr) {
  extern __shared__ char smem[];
  unsigned char* R0 = (unsigned char*)smem;            // 64 KB
  unsigned char* R1 = (unsigned char*)(smem + 65536);  // 64 KB
  float*    cjl    = (float*)(smem + 131072);          // 1024 f32
  unsigned* keys_l = (unsigned*)(smem + 135168);       // 128 u32
  float*    xn_l   = (float*)(smem + 135680);          // 128 f32
  float*    red    = (float*)(smem + 136192);          // 8 f32

  int n0  = blockIdx.x * 128;
  int b   = n0 >> 12;
  int hw0 = n0 & 4095;
  int t    = threadIdx.x;
  int w    = t >> 6, lane = t & 63;
  int quad = lane >> 4, lr = lane & 15;
  int g = w >> 1;        // n-group 0..3
  int h = w & 1;         // k-half

  // stage B(kt=0) early so HBM/L2 latency hides under the transpose
  stage_b(embbf, R1, 0, t);

  for (int i = t; i < 1024; i += 512) cjl[i] = 0.375f - 0.5f * enorm[i];
  if (t < 128) { keys_l[t] = 0u; xn_l[t] = 0.f; }
  __syncthreads();

  // ---- A prologue: x[c][hw] -> A_lds[n][c] bf16 (swizzled) + xnorm ----
  {
    int nl = (w & 1) * 64 + lane;      // n-local 0..127
    const float* xp = x + (size_t)b * (EMB_C * HWB) + hw0 + nl;
    float xn = 0.f;
#pragma unroll
    for (int o = 0; o < 8; ++o) {
      int cc = (w >> 1) * 8 + o;       // c-chunk 0..31 (8 c each)
      float v[8];
#pragma unroll
      for (int j = 0; j < 8; ++j) {
        v[j] = xp[(size_t)(cc * 8 + j) * HWB];   // 256B-coalesced per instr
        xn += v[j] * v[j];
      }
      union { unsigned u[4]; uint4 q; } pk;
#pragma unroll
      for (int m = 0; m < 4; ++m)
        pk.u[m] = (unsigned)bf16bits(v[2 * m]) | ((unsigned)bf16bits(v[2 * m + 1]) << 16);
      int pos = ((cc >> 3) << 3) | ((cc & 7) ^ (nl & 7));
      *(uint4*)(R0 + nl * 512 + pos * 16) = pk.q;
    }
    atomicAdd(&xn_l[nl], xn);          // 4 partials per n (one per c-quarter)
  }
  __syncthreads();   // A complete; B0 glds drained; xn_l final

  // ---- A fragments into registers (64 VGPRs) ----
  bf16x8 af[2][8];
#pragma unroll
  for (int i = 0; i < 2; ++i) {
    int rA = g * 32 + i * 16 + lr;
#pragma unroll
    for (int s = 0; s < 8; ++s) {
      int cc = s * 4 + quad;
      int pos = ((cc >> 3) << 3) | ((cc & 7) ^ (rA & 7));
      af[i][s] = *(const bf16x8*)(R0 + rA * 512 + pos * 16);
    }
  }
  __syncthreads();   // af loaded; R0 becomes B ping buffer

  // ---- K-loop: 8 k-tiles of 128 k, B double-buffered ----
  unsigned best[2][4] = {{0u,0u,0u,0u},{0u,0u,0u,0u}};
  for (int kt = 0; kt < 8; ++kt) {
    unsigned char* srcB = (kt & 1) ? R0 : R1;
    unsigned char* dstB = (kt & 1) ? R1 : R0;
    if (kt < 7) stage_b(embbf, dstB, kt + 1, t);
    float cj[4]; unsigned kp[4];
#pragma unroll
    for (int j = 0; j < 4; ++j) {
      int k = kt * 128 + h * 64 + j * 16 + lr;
      cj[j] = cjl[k];
      kp[j] = 1023u - (unsigned)k;
    }
    f32x4 acc[2][4] = {};
#pragma unroll
    for (int s = 0; s < 8; ++s) {
      bf16x8 bf[4];
#pragma unroll
      for (int j = 0; j < 4; ++j) {
        int rB = h * 64 + j * 16 + lr;
        int cc = s * 4 + quad;
        int pos = ((cc >> 3) << 3) | ((cc & 7) ^ (rB & 7));
        bf[j] = *(const bf16x8*)(srcB + rB * 512 + pos * 16);
      }
#pragma unroll
      for (int i = 0; i < 2; ++i)
#pragma unroll
        for (int j = 0; j < 4; ++j)
          acc[i][j] = __builtin_amdgcn_mfma_f32_16x16x32_bf16(af[i][s], bf[j], acc[i][j], 0, 0, 0);
    }
    // fold argmin keys: f = dot + 0.375 - 0.5||e||^2 in (0.04,0.71) -> positive
    // float u32-order-correct; low 10 mantissa bits carry (1023-k).
#pragma unroll
    for (int i = 0; i < 2; ++i)
#pragma unroll
      for (int j = 0; j < 4; ++j)
#pragma unroll
        for (int r = 0; r < 4; ++r) {
          float f = acc[i][j][r] + cj[j];
          unsigned key = (__float_as_uint(f) & 0xFFFFFC00u) | kp[j];
          best[i][r] = best[i][r] > key ? best[i][r] : key;
        }
    __syncthreads();   // srcB reads done before it becomes next dst; dst visible
  }

  // ---- combine keys across k-lanes and k-halves ----
#pragma unroll
  for (int i = 0; i < 2; ++i)
#pragma unroll
    for (int r = 0; r < 4; ++r) {
      unsigned v = best[i][r];
#pragma unroll
      for (int m = 1; m < 16; m <<= 1) {
        unsigned o = (unsigned)__shfl_xor((int)v, m, 64);
        v = v > o ? v : o;
      }
      if (lr == 0) atomicMax(&keys_l[g * 32 + i * 16 + quad * 4 + r], v);
    }
  __syncthreads();

  // ---- loss partial: d2 = ||x||^2 + 0.75 - 2*f_hat ----
  if (t < 128) {
    unsigned key = keys_l[t];
    float fh = __uint_as_float(key & 0xFFFFFC00u);
    float lsum = xn_l[t] + 0.75f - 2.0f * fh;
    for (int m = 32; m; m >>= 1) lsum += __shfl_down(lsum, m, 64);
    if (lane == 0) red[w] = lsum;
  }
  __syncthreads();
  if (t == 0) {
    atomicAdd(loss, red[0] + red[1]);
    __threadfence();
  }

  // ---- output: gather emb rows -> LDS [128c][128n] tile -> c-major stores ----
  float* tile = (float*)R0;
  int nl  = t & 127;
  int cs  = (t >> 7) * 32;
  int idx = 1023 - (int)(keys_l[nl] & 1023u);
  float* ob = out + 1 + (size_t)b * (EMB_C * HWB) + hw0;
  for (int hc = 0; hc < 2; ++hc) {
    if (hc) __syncthreads();
    const float* er = emb + (size_t)idx * EMB_C + hc * 128 + cs;
#pragma unroll
    for (int m = 0; m < 8; ++m) {
      f32x4 q = *(const f32x4*)(er + m * 4);     // L2-resident emb gather
      tile[(cs + m * 4 + 0) * 128 + nl] = q[0];
      tile[(cs + m * 4 + 1) * 128 + nl] = q[1];
      tile[(cs + m * 4 + 2) * 128 + nl] = q[2];
      tile[(cs + m * 4 + 3) * 128 + nl] = q[3];
    }
    __syncthreads();
#pragma unroll
    for (int s2 = 0; s2 < 32; ++s2) {
      int id = s2 * 512 + t;
      int cl = id >> 7;        // 0..127
      int nn = id & 127;       // 64 consecutive per wave -> 256B stores
      ob[(size_t)(hc * 128 + cl) * HWB + nn] = tile[cl * 128 + nn];
    }
  }

  // ---- fused finalize: last block writes out[0] ----
  if (t == 0) {
    unsigned done = atomicAdd(ctr, 1u);
    if (done == gridDim.x - 1) {
      float total = atomicAdd(loss, 0.f);   // device-scope read of final sum
      out[0] = 1.0625f * total / 16777216.0f;
    }
  }
}

extern "C" void kernel_launch(void* const* d_in, const int* in_sizes, int n_in,
                              void* d_out, int out_size, void* d_ws, size_t ws_size,
                              hipStream_t stream) {
  const float* x   = (const float*)d_in[0];   // [16,256,64,64]
  const float* emb = (const float*)d_in[1];   // [1024,256]
  float* out = (float*)d_out;                 // [1 + 16777216]
  char*  ws  = (char*)d_ws;

  unsigned short* emb_bf = (unsigned short*)ws;                 // 512 KB
  float*          enorm  = (float*)(ws + 524288);               // 4 KB
  float*          loss   = (float*)(ws + 528384);               // 4 B
  unsigned*       ctr    = (unsigned*)(ws + 528388);            // 4 B

  // allow >64KB dynamic LDS (idempotent, capture-safe — proven R4)
  hipFuncSetAttribute((const void*)k_main,
                      hipFuncAttributeMaxDynamicSharedMemorySize, LDS_BYTES);

  k_emb <<<dim3(EMB_K), dim3(EMB_C), 0, stream>>>(emb, emb_bf, enorm, loss, ctr);
  k_main<<<dim3(NPIX / 128), dim3(512), LDS_BYTES, stream>>>(x, emb, emb_bf, enorm,
                                                             out, loss, ctr);
}